// Round 5
// baseline (155.816 us; speedup 1.0000x reference)
//
#include <hip/hip_runtime.h>

#define BATCH 32
#define CH    256
#define HWPX  3136   // 56*56
#define WIDTH 56
#define NK    16
#define NSLAB 28     // kpmat pixel slabs per batch (112 px each)
#define NSUB  4      // kkvec channel split (global partials)
#define EPSV  1e-5f
#define SPITCH 68    // kconv LDS row pitch: non-mod-32 banks + 16B-aligned

// ---------------------------------------------------------------------------
// Kernel 1: K-partials. Kpart[s][b,n,k] = sum_{c in sub s} k_w[k,c]*BN(x[b,c,n])
// grid: 4 subs x 196 blocks, 256 threads; thread = 2 pixels (float2, 8B/lane
// -> 512B/wave-load), 64 channels, 8 loads in flight. (R3->R4: 117 -> <73us)
// ---------------------------------------------------------------------------
__global__ __launch_bounds__(256, 6) void kkvec(
    const float* __restrict__ x,
    const float* __restrict__ gamma, const float* __restrict__ beta,
    const float* __restrict__ mean,  const float* __restrict__ var,
    const float* __restrict__ kw,    float* __restrict__ Kpart)
{
    const int sub = blockIdx.x / 196;           // 0..3, block-uniform
    const int pb  = blockIdx.x % 196;
    const int job = pb * 256 + threadIdx.x;     // 0..50175 = b*1568 + px2
    const int b   = job / 1568;
    const int px2 = job % 1568;                 // float2 index in plane
    const int cbase = sub * 64;
    const float* xp = x + ((size_t)b * CH + cbase) * HWPX + px2 * 2;

    float acc0[NK], acc1[NK];
#pragma unroll
    for (int k = 0; k < NK; ++k) { acc0[k] = 0.f; acc1[k] = 0.f; }

    for (int c0 = 0; c0 < 64; c0 += 8) {
        float2 v[8];
#pragma unroll
        for (int i = 0; i < 8; ++i)             // 8 x 512B wave-loads in flight
            v[i] = *(const float2*)(xp + (size_t)(c0 + i) * HWPX);
#pragma unroll
        for (int i = 0; i < 8; ++i) {           // BN (params wave-uniform)
            const int c = cbase + c0 + i;
            const float sc = gamma[c] * rsqrtf(var[c] + EPSV);
            const float sh = fmaf(-mean[c], sc, beta[c]);
            v[i].x = fmaf(v[i].x, sc, sh);
            v[i].y = fmaf(v[i].y, sc, sh);
        }
#pragma unroll
        for (int k = 0; k < NK; ++k) {
            const float4 w0 = *(const float4*)(kw + k * CH + cbase + c0);     // uniform
            const float4 w1 = *(const float4*)(kw + k * CH + cbase + c0 + 4); // uniform
            acc0[k] = fmaf(v[0].x, w0.x, acc0[k]); acc1[k] = fmaf(v[0].y, w0.x, acc1[k]);
            acc0[k] = fmaf(v[1].x, w0.y, acc0[k]); acc1[k] = fmaf(v[1].y, w0.y, acc1[k]);
            acc0[k] = fmaf(v[2].x, w0.z, acc0[k]); acc1[k] = fmaf(v[2].y, w0.z, acc1[k]);
            acc0[k] = fmaf(v[3].x, w0.w, acc0[k]); acc1[k] = fmaf(v[3].y, w0.w, acc1[k]);
            acc0[k] = fmaf(v[4].x, w1.x, acc0[k]); acc1[k] = fmaf(v[4].y, w1.x, acc1[k]);
            acc0[k] = fmaf(v[5].x, w1.y, acc0[k]); acc1[k] = fmaf(v[5].y, w1.y, acc1[k]);
            acc0[k] = fmaf(v[6].x, w1.z, acc0[k]); acc1[k] = fmaf(v[6].y, w1.z, acc1[k]);
            acc0[k] = fmaf(v[7].x, w1.w, acc0[k]); acc1[k] = fmaf(v[7].y, w1.w, acc1[k]);
        }
    }

    float* op = Kpart + ((size_t)sub * BATCH * HWPX + (size_t)b * HWPX + px2 * 2) * NK;
#pragma unroll
    for (int kq = 0; kq < 4; ++kq)
        ((float4*)op)[kq] = make_float4(acc0[kq*4+0], acc0[kq*4+1], acc0[kq*4+2], acc0[kq*4+3]);
#pragma unroll
    for (int kq = 0; kq < 4; ++kq)
        ((float4*)op)[4+kq] = make_float4(acc1[kq*4+0], acc1[kq*4+1], acc1[kq*4+2], acc1[kq*4+3]);
}

// ---------------------------------------------------------------------------
// Kernel 1b: K = sum of 4 Kpart planes. float4 jobs, fully coalesced.
// ---------------------------------------------------------------------------
__global__ __launch_bounds__(256) void ksum(
    const float* __restrict__ Kpart, float* __restrict__ Kbuf)
{
    const int i = blockIdx.x * 256 + threadIdx.x;   // 0..401407 float4 jobs
    const float4* p = (const float4*)Kpart;
    float4 s = p[i];
#pragma unroll
    for (int s2 = 1; s2 < NSUB; ++s2) {
        const float4 v = p[(size_t)s2 * 401408 + i];
        s.x += v.x; s.y += v.y; s.z += v.z; s.w += v.w;
    }
    ((float4*)Kbuf)[i] = s;
}

// ---------------------------------------------------------------------------
// Kernel 2: P_part[b,nb,c,k] = sum_{n in 112-px slab} BN(x[b,c,n]) * K[b,n,k]
// grid: 32*28 blocks, 256 threads; thread = channel row (14 waves/CU).
// ---------------------------------------------------------------------------
__global__ __launch_bounds__(256) void kpmat(
    const float* __restrict__ x,
    const float* __restrict__ gamma, const float* __restrict__ beta,
    const float* __restrict__ mean,  const float* __restrict__ var,
    const float* __restrict__ Kbuf,  float* __restrict__ Pp)
{
    const int b  = blockIdx.x / NSLAB;
    const int nb = blockIdx.x % NSLAB;
    const int n0 = nb * 112;
    const int c  = threadIdx.x;

    const float sc = gamma[c] * rsqrtf(var[c] + EPSV);
    const float sh = fmaf(-mean[c], sc, beta[c]);

    const float4* xr = (const float4*)(x + ((size_t)b * CH + c) * HWPX + n0);
    const float*  Kp = Kbuf + ((size_t)b * HWPX + n0) * NK;

    float acc[NK];
#pragma unroll
    for (int k = 0; k < NK; ++k) acc[k] = 0.f;

#pragma unroll 4
    for (int j = 0; j < 28; ++j) {
        const float4 xv = xr[j];
        float v[4];
        v[0] = fmaf(xv.x, sc, sh); v[1] = fmaf(xv.y, sc, sh);
        v[2] = fmaf(xv.z, sc, sh); v[3] = fmaf(xv.w, sc, sh);
#pragma unroll
        for (int d = 0; d < 4; ++d) {
            const float vd = v[d];
#pragma unroll
            for (int kq = 0; kq < 4; ++kq) {
                const float4 kv = *(const float4*)(Kp + ((j*4 + d) * NK) + kq*4); // uniform
                acc[kq*4+0] = fmaf(vd, kv.x, acc[kq*4+0]);
                acc[kq*4+1] = fmaf(vd, kv.y, acc[kq*4+1]);
                acc[kq*4+2] = fmaf(vd, kv.z, acc[kq*4+2]);
                acc[kq*4+3] = fmaf(vd, kv.w, acc[kq*4+3]);
            }
        }
    }
    float4* op = (float4*)(Pp + (((size_t)b * NSLAB + nb) * CH + c) * NK);
#pragma unroll
    for (int kq = 0; kq < 4; ++kq)
        op[kq] = make_float4(acc[kq*4+0], acc[kq*4+1], acc[kq*4+2], acc[kq*4+3]);
}

// ---------------------------------------------------------------------------
// Kernel 2b: reduce slab partials Pp[b][28][CH*NK] -> P[b][CH*NK]
// ---------------------------------------------------------------------------
__global__ __launch_bounds__(256) void kpred(
    const float* __restrict__ Pp, float* __restrict__ P)
{
    const int idx = blockIdx.x * 256 + threadIdx.x;   // 32*4096 total
    const int b = idx >> 12;
    const int e = idx & 4095;
    const float* p = Pp + (size_t)b * NSLAB * 4096 + e;
    float s = 0.f;
#pragma unroll
    for (int nb = 0; nb < NSLAB; ++nb) s += p[(size_t)nb * 4096];
    P[idx] = s;
}

// ---------------------------------------------------------------------------
// Kernel 3: S = q_w @ P; attn = softmax(S/512) over k; wgt = attn @ bank.
// ---------------------------------------------------------------------------
__global__ __launch_bounds__(256) void ksoft(
    const float* __restrict__ P, const float* __restrict__ qw,
    const float* __restrict__ bank, float* __restrict__ wgt)
{
    const int b  = blockIdx.x >> 3;
    const int cb = blockIdx.x & 7;
    const int tid = threadIdx.x;

    __shared__ float s_P[CH * NK];       // full P[b] (16 KB)
    __shared__ float s_red[32 * 8 * NK]; // partial S (16 KB)
    __shared__ float s_S[32 * NK];
    __shared__ float s_attn[32 * NK];

    for (int idx = tid; idx < CH * NK; idx += 256)
        s_P[idx] = P[(size_t)b * CH * NK + idx];
    __syncthreads();

    const int c_l = tid & 31, sub = tid >> 5;
    const int c = cb * 32 + c_l;
    float a[NK];
#pragma unroll
    for (int k = 0; k < NK; ++k) a[k] = 0.f;
    const float* qrow = qw + (size_t)c * CH + sub * 32;
    for (int j = 0; j < 32; ++j) {
        const float qv = qrow[j];
        const float4* p4 = (const float4*)&s_P[(sub * 32 + j) * NK];
#pragma unroll
        for (int kq = 0; kq < 4; ++kq) {
            const float4 pv = p4[kq];
            a[kq*4+0] = fmaf(qv, pv.x, a[kq*4+0]);
            a[kq*4+1] = fmaf(qv, pv.y, a[kq*4+1]);
            a[kq*4+2] = fmaf(qv, pv.z, a[kq*4+2]);
            a[kq*4+3] = fmaf(qv, pv.w, a[kq*4+3]);
        }
    }
#pragma unroll
    for (int kq = 0; kq < 4; ++kq)
        *(float4*)&s_red[(c_l * 8 + sub) * NK + kq*4] =
            make_float4(a[kq*4+0], a[kq*4+1], a[kq*4+2], a[kq*4+3]);
    __syncthreads();

    for (int idx = tid; idx < 32 * NK; idx += 256) {
        const int cl = idx >> 4, k = idx & 15;
        float s = 0.f;
#pragma unroll
        for (int s2 = 0; s2 < 8; ++s2) s += s_red[(cl * 8 + s2) * NK + k];
        s_S[idx] = s * (1.f / 512.f);
    }
    __syncthreads();

    if (tid < 32) {
        float l[NK];
#pragma unroll
        for (int k = 0; k < NK; ++k) l[k] = s_S[tid * NK + k];
        float m = l[0];
#pragma unroll
        for (int k = 1; k < NK; ++k) m = fmaxf(m, l[k]);
        float sum = 0.f;
#pragma unroll
        for (int k = 0; k < NK; ++k) { l[k] = __expf(l[k] - m); sum += l[k]; }
        const float inv = 1.f / sum;
#pragma unroll
        for (int k = 0; k < NK; ++k) s_attn[tid * NK + k] = l[k] * inv;
    }
    __syncthreads();

    for (int idx = tid; idx < 32 * 49; idx += 256) {
        const int cl = idx / 49, e = idx - cl * 49;
        float wv = 0.f;
#pragma unroll
        for (int k = 0; k < NK; ++k)
            wv = fmaf(s_attn[cl * NK + k], bank[k * 49 + e], wv);
        wgt[((size_t)b * CH + cb * 32 + cl) * 49 + e] = wv;
    }
}

// ---------------------------------------------------------------------------
// Kernel 4: depthwise 7x7 'same' conv, per-(b,c) dynamic kernel + bias.
// grid: 8192 blocks (one 56x56 plane), 256 threads; thread = 4x4 output tile.
// R4 lesson: stride-64 LDS rows (mod-32-bank) + unaligned scalar ds_writes ->
// 2.2e7 bank-conflict cycles (~half the kernel). Fix: pitch 68 (row bank map
// rotates by 1 quad/row) + left-pad 4 so staging writes AND compute reads are
// 16B-aligned b128. Tap index becomes rr[ix+kx+1].
// ---------------------------------------------------------------------------
__global__ __launch_bounds__(256) void kconv(
    const float* __restrict__ x, const float* __restrict__ wgt,
    const float* __restrict__ bias, float* __restrict__ out)
{
    const int bc  = blockIdx.x;
    const int cch = bc & 255;
    const int tid = threadIdx.x;

    __shared__ __align__(16) float s_p[62 * SPITCH];   // 16.9 KB
    __shared__ float s_w[64];

    const float4 z4 = make_float4(0.f, 0.f, 0.f, 0.f);
    for (int i = tid; i < (62 * SPITCH) / 4; i += 256) ((float4*)s_p)[i] = z4;
    if (tid < 49) s_w[tid] = wgt[(size_t)bc * 49 + tid];
    __syncthreads();

    // image col ic lives at s_p col ic+4; rows 0..2 / 59..61 and cols 0..3 /
    // 60..67 stay zero (halo).
    const float4* xp4 = (const float4*)(x + (size_t)bc * HWPX);
    for (int i = tid; i < 784; i += 256) {
        const float4 v = xp4[i];
        const int y = i / 14, q = i - y * 14;
        *(float4*)&s_p[(y + 3) * SPITCH + 4 * q + 4] = v;   // aligned b128
    }
    __syncthreads();

    float w[49];
#pragma unroll
    for (int i = 0; i < 49; ++i) w[i] = s_w[i];
    const float bv = bias[cch];

    if (tid < 196) {
        const int ty = (tid / 14) * 4, tx = (tid % 14) * 4;
        float acc[16];
#pragma unroll
        for (int i = 0; i < 16; ++i) acc[i] = bv;

#pragma unroll
        for (int ri = 0; ri < 10; ++ri) {
            const float* row = &s_p[(ty + ri) * SPITCH + tx];
            const float4 r0 = *(const float4*)(row);        // aligned b128
            const float4 r1 = *(const float4*)(row + 4);
            const float4 r2 = *(const float4*)(row + 8);
            float rr[12];
            rr[0]=r0.x; rr[1]=r0.y; rr[2]=r0.z;  rr[3]=r0.w;
            rr[4]=r1.x; rr[5]=r1.y; rr[6]=r1.z;  rr[7]=r1.w;
            rr[8]=r2.x; rr[9]=r2.y; rr[10]=r2.z; rr[11]=r2.w;
#pragma unroll
            for (int iy = 0; iy < 4; ++iy) {
                const int ky = ri - iy;
                if (ky < 0 || ky > 6) continue;   // compile-time pruned
#pragma unroll
                for (int ix = 0; ix < 4; ++ix) {
#pragma unroll
                    for (int kx = 0; kx < 7; ++kx)
                        acc[iy*4+ix] = fmaf(w[ky*7+kx], rr[ix+kx+1], acc[iy*4+ix]);
                }
            }
        }
#pragma unroll
        for (int iy = 0; iy < 4; ++iy) {
            float* op = out + (size_t)bc * HWPX + (ty + iy) * WIDTH + tx;
            *(float4*)op = make_float4(acc[iy*4+0], acc[iy*4+1], acc[iy*4+2], acc[iy*4+3]);
        }
    }
}

// ---------------------------------------------------------------------------
extern "C" void kernel_launch(void* const* d_in, const int* in_sizes, int n_in,
                              void* d_out, int out_size, void* d_ws, size_t ws_size,
                              hipStream_t stream)
{
    const float* x     = (const float*)d_in[0];
    const float* gamma = (const float*)d_in[1];
    const float* beta  = (const float*)d_in[2];
    const float* mean  = (const float*)d_in[3];
    const float* var   = (const float*)d_in[4];
    const float* qw    = (const float*)d_in[5];
    const float* kw    = (const float*)d_in[6];
    const float* bank  = (const float*)d_in[7];
    const float* bias  = (const float*)d_in[8];
    float* out = (float*)d_out;

    // ws layout (34.2 MB): Kpart is dead after ksum, so Pp aliases it.
    float* ws    = (float*)d_ws;
    float* Kpart = ws;                                   // 4*32*3136*16 = 6,422,528 f
    float* Pp    = ws;                                   // alias: 32*28*4096 = 3,670,016 f
    float* Kbuf  = ws + (size_t)NSUB * BATCH * HWPX * NK;   // 1,605,632 f
    float* P     = Kbuf + (size_t)BATCH * HWPX * NK;        //   131,072 f
    float* wgt   = P + (size_t)BATCH * CH * NK;             //   401,408 f

    kkvec<<<dim3(NSUB * 196),   dim3(256), 0, stream>>>(x, gamma, beta, mean, var, kw, Kpart);
    ksum <<<dim3(1568),         dim3(256), 0, stream>>>(Kpart, Kbuf);
    kpmat<<<dim3(BATCH * NSLAB),dim3(256), 0, stream>>>(x, gamma, beta, mean, var, Kbuf, Pp);
    kpred<<<dim3(512),          dim3(256), 0, stream>>>(Pp, P);
    ksoft<<<dim3(BATCH * 8),    dim3(256), 0, stream>>>(P, qw, bank, wgt);
    kconv<<<dim3(BATCH * CH),   dim3(256), 0, stream>>>(x, wgt, bias, out);
}

// Round 6
// 150.232 us; speedup vs baseline: 1.0372x; 1.0372x over previous
//
#include <hip/hip_runtime.h>

#define BATCH 32
#define CH    256
#define HWPX  3136   // 56*56
#define WIDTH 56
#define NK    16
#define NSLAB 28     // kpmat pixel slabs per batch (112 px each)
#define NSUB  4      // kkvec channel split (global partials)
#define EPSV  1e-5f
#define SPITCH 68    // kconv LDS row pitch (17 chunks; 17 mod 8 = 1)
#define SROWS  70    // 3 halo + 56 + up to row 69 read by tile row 15

// ---------------------------------------------------------------------------
// Kernel 1: K-partials. Kpart[s][b,n,k] = sum_{c in sub s} k_w[k,c]*BN(x[b,c,n])
// grid: 4 subs x 196 blocks, 256 threads; thread = 2 pixels (float2, 8B/lane
// -> 512B/wave-load), 64 channels, 8 loads in flight. (R3->R4: 117 -> <73us)
// ---------------------------------------------------------------------------
__global__ __launch_bounds__(256, 6) void kkvec(
    const float* __restrict__ x,
    const float* __restrict__ gamma, const float* __restrict__ beta,
    const float* __restrict__ mean,  const float* __restrict__ var,
    const float* __restrict__ kw,    float* __restrict__ Kpart)
{
    const int sub = blockIdx.x / 196;           // 0..3, block-uniform
    const int pb  = blockIdx.x % 196;
    const int job = pb * 256 + threadIdx.x;     // 0..50175 = b*1568 + px2
    const int b   = job / 1568;
    const int px2 = job % 1568;                 // float2 index in plane
    const int cbase = sub * 64;
    const float* xp = x + ((size_t)b * CH + cbase) * HWPX + px2 * 2;

    float acc0[NK], acc1[NK];
#pragma unroll
    for (int k = 0; k < NK; ++k) { acc0[k] = 0.f; acc1[k] = 0.f; }

    for (int c0 = 0; c0 < 64; c0 += 8) {
        float2 v[8];
#pragma unroll
        for (int i = 0; i < 8; ++i)             // 8 x 512B wave-loads in flight
            v[i] = *(const float2*)(xp + (size_t)(c0 + i) * HWPX);
#pragma unroll
        for (int i = 0; i < 8; ++i) {           // BN (params wave-uniform)
            const int c = cbase + c0 + i;
            const float sc = gamma[c] * rsqrtf(var[c] + EPSV);
            const float sh = fmaf(-mean[c], sc, beta[c]);
            v[i].x = fmaf(v[i].x, sc, sh);
            v[i].y = fmaf(v[i].y, sc, sh);
        }
#pragma unroll
        for (int k = 0; k < NK; ++k) {
            const float4 w0 = *(const float4*)(kw + k * CH + cbase + c0);     // uniform
            const float4 w1 = *(const float4*)(kw + k * CH + cbase + c0 + 4); // uniform
            acc0[k] = fmaf(v[0].x, w0.x, acc0[k]); acc1[k] = fmaf(v[0].y, w0.x, acc1[k]);
            acc0[k] = fmaf(v[1].x, w0.y, acc0[k]); acc1[k] = fmaf(v[1].y, w0.y, acc1[k]);
            acc0[k] = fmaf(v[2].x, w0.z, acc0[k]); acc1[k] = fmaf(v[2].y, w0.z, acc1[k]);
            acc0[k] = fmaf(v[3].x, w0.w, acc0[k]); acc1[k] = fmaf(v[3].y, w0.w, acc1[k]);
            acc0[k] = fmaf(v[4].x, w1.x, acc0[k]); acc1[k] = fmaf(v[4].y, w1.x, acc1[k]);
            acc0[k] = fmaf(v[5].x, w1.y, acc0[k]); acc1[k] = fmaf(v[5].y, w1.y, acc1[k]);
            acc0[k] = fmaf(v[6].x, w1.z, acc0[k]); acc1[k] = fmaf(v[6].y, w1.z, acc1[k]);
            acc0[k] = fmaf(v[7].x, w1.w, acc0[k]); acc1[k] = fmaf(v[7].y, w1.w, acc1[k]);
        }
    }

    float* op = Kpart + ((size_t)sub * BATCH * HWPX + (size_t)b * HWPX + px2 * 2) * NK;
#pragma unroll
    for (int kq = 0; kq < 4; ++kq)
        ((float4*)op)[kq] = make_float4(acc0[kq*4+0], acc0[kq*4+1], acc0[kq*4+2], acc0[kq*4+3]);
#pragma unroll
    for (int kq = 0; kq < 4; ++kq)
        ((float4*)op)[4+kq] = make_float4(acc1[kq*4+0], acc1[kq*4+1], acc1[kq*4+2], acc1[kq*4+3]);
}

// ---------------------------------------------------------------------------
// Kernel 1b: K = sum of 4 Kpart planes. float4 jobs, fully coalesced.
// ---------------------------------------------------------------------------
__global__ __launch_bounds__(256) void ksum(
    const float* __restrict__ Kpart, float* __restrict__ Kbuf)
{
    const int i = blockIdx.x * 256 + threadIdx.x;   // 0..401407 float4 jobs
    const float4* p = (const float4*)Kpart;
    float4 s = p[i];
#pragma unroll
    for (int s2 = 1; s2 < NSUB; ++s2) {
        const float4 v = p[(size_t)s2 * 401408 + i];
        s.x += v.x; s.y += v.y; s.z += v.z; s.w += v.w;
    }
    ((float4*)Kbuf)[i] = s;
}

// ---------------------------------------------------------------------------
// Kernel 2: P_part[b,nb,c,k] = sum_{n in 112-px slab} BN(x[b,c,n]) * K[b,n,k]
// grid: 32*28 blocks, 256 threads; thread = channel row (14 waves/CU).
// ---------------------------------------------------------------------------
__global__ __launch_bounds__(256) void kpmat(
    const float* __restrict__ x,
    const float* __restrict__ gamma, const float* __restrict__ beta,
    const float* __restrict__ mean,  const float* __restrict__ var,
    const float* __restrict__ Kbuf,  float* __restrict__ Pp)
{
    const int b  = blockIdx.x / NSLAB;
    const int nb = blockIdx.x % NSLAB;
    const int n0 = nb * 112;
    const int c  = threadIdx.x;

    const float sc = gamma[c] * rsqrtf(var[c] + EPSV);
    const float sh = fmaf(-mean[c], sc, beta[c]);

    const float4* xr = (const float4*)(x + ((size_t)b * CH + c) * HWPX + n0);
    const float*  Kp = Kbuf + ((size_t)b * HWPX + n0) * NK;

    float acc[NK];
#pragma unroll
    for (int k = 0; k < NK; ++k) acc[k] = 0.f;

#pragma unroll 4
    for (int j = 0; j < 28; ++j) {
        const float4 xv = xr[j];
        float v[4];
        v[0] = fmaf(xv.x, sc, sh); v[1] = fmaf(xv.y, sc, sh);
        v[2] = fmaf(xv.z, sc, sh); v[3] = fmaf(xv.w, sc, sh);
#pragma unroll
        for (int d = 0; d < 4; ++d) {
            const float vd = v[d];
#pragma unroll
            for (int kq = 0; kq < 4; ++kq) {
                const float4 kv = *(const float4*)(Kp + ((j*4 + d) * NK) + kq*4); // uniform
                acc[kq*4+0] = fmaf(vd, kv.x, acc[kq*4+0]);
                acc[kq*4+1] = fmaf(vd, kv.y, acc[kq*4+1]);
                acc[kq*4+2] = fmaf(vd, kv.z, acc[kq*4+2]);
                acc[kq*4+3] = fmaf(vd, kv.w, acc[kq*4+3]);
            }
        }
    }
    float4* op = (float4*)(Pp + (((size_t)b * NSLAB + nb) * CH + c) * NK);
#pragma unroll
    for (int kq = 0; kq < 4; ++kq)
        op[kq] = make_float4(acc[kq*4+0], acc[kq*4+1], acc[kq*4+2], acc[kq*4+3]);
}

// ---------------------------------------------------------------------------
// Kernel 2b: reduce slab partials Pp[b][28][CH*NK] -> P[b][CH*NK]
// ---------------------------------------------------------------------------
__global__ __launch_bounds__(256) void kpred(
    const float* __restrict__ Pp, float* __restrict__ P)
{
    const int idx = blockIdx.x * 256 + threadIdx.x;   // 32*4096 total
    const int b = idx >> 12;
    const int e = idx & 4095;
    const float* p = Pp + (size_t)b * NSLAB * 4096 + e;
    float s = 0.f;
#pragma unroll
    for (int nb = 0; nb < NSLAB; ++nb) s += p[(size_t)nb * 4096];
    P[idx] = s;
}

// ---------------------------------------------------------------------------
// Kernel 3: S = q_w @ P; attn = softmax(S/512) over k; wgt = attn @ bank.
// ---------------------------------------------------------------------------
__global__ __launch_bounds__(256) void ksoft(
    const float* __restrict__ P, const float* __restrict__ qw,
    const float* __restrict__ bank, float* __restrict__ wgt)
{
    const int b  = blockIdx.x >> 3;
    const int cb = blockIdx.x & 7;
    const int tid = threadIdx.x;

    __shared__ float s_P[CH * NK];       // full P[b] (16 KB)
    __shared__ float s_red[32 * 8 * NK]; // partial S (16 KB)
    __shared__ float s_S[32 * NK];
    __shared__ float s_attn[32 * NK];

    for (int idx = tid; idx < CH * NK; idx += 256)
        s_P[idx] = P[(size_t)b * CH * NK + idx];
    __syncthreads();

    const int c_l = tid & 31, sub = tid >> 5;
    const int c = cb * 32 + c_l;
    float a[NK];
#pragma unroll
    for (int k = 0; k < NK; ++k) a[k] = 0.f;
    const float* qrow = qw + (size_t)c * CH + sub * 32;
    for (int j = 0; j < 32; ++j) {
        const float qv = qrow[j];
        const float4* p4 = (const float4*)&s_P[(sub * 32 + j) * NK];
#pragma unroll
        for (int kq = 0; kq < 4; ++kq) {
            const float4 pv = p4[kq];
            a[kq*4+0] = fmaf(qv, pv.x, a[kq*4+0]);
            a[kq*4+1] = fmaf(qv, pv.y, a[kq*4+1]);
            a[kq*4+2] = fmaf(qv, pv.z, a[kq*4+2]);
            a[kq*4+3] = fmaf(qv, pv.w, a[kq*4+3]);
        }
    }
#pragma unroll
    for (int kq = 0; kq < 4; ++kq)
        *(float4*)&s_red[(c_l * 8 + sub) * NK + kq*4] =
            make_float4(a[kq*4+0], a[kq*4+1], a[kq*4+2], a[kq*4+3]);
    __syncthreads();

    for (int idx = tid; idx < 32 * NK; idx += 256) {
        const int cl = idx >> 4, k = idx & 15;
        float s = 0.f;
#pragma unroll
        for (int s2 = 0; s2 < 8; ++s2) s += s_red[(cl * 8 + s2) * NK + k];
        s_S[idx] = s * (1.f / 512.f);
    }
    __syncthreads();

    if (tid < 32) {
        float l[NK];
#pragma unroll
        for (int k = 0; k < NK; ++k) l[k] = s_S[tid * NK + k];
        float m = l[0];
#pragma unroll
        for (int k = 1; k < NK; ++k) m = fmaxf(m, l[k]);
        float sum = 0.f;
#pragma unroll
        for (int k = 0; k < NK; ++k) { l[k] = __expf(l[k] - m); sum += l[k]; }
        const float inv = 1.f / sum;
#pragma unroll
        for (int k = 0; k < NK; ++k) s_attn[tid * NK + k] = l[k] * inv;
    }
    __syncthreads();

    for (int idx = tid; idx < 32 * 49; idx += 256) {
        const int cl = idx / 49, e = idx - cl * 49;
        float wv = 0.f;
#pragma unroll
        for (int k = 0; k < NK; ++k)
            wv = fmaf(s_attn[cl * NK + k], bank[k * 49 + e], wv);
        wgt[((size_t)b * CH + cb * 32 + cl) * 49 + e] = wv;
    }
}

// ---------------------------------------------------------------------------
// Kernel 4: depthwise 7x7 'same' conv, per-(b,c) dynamic kernel + bias.
// grid: 8192 blocks (one plane), 256 threads = 16x16 grid of 4x4 tiles.
// R5 lesson: 14-wide tile grid + ty step 4 -> chunk-residue profile
// [3,3,2,2,2,2,1,1] per 16 lanes -> LDS read conflicts regardless of pitch.
// Fix: 16x16 tile grid; residue (4*tyi + q0) mod 8 covers every residue
// exactly 2x per 16 lanes == canonical conflict-free b128 profile, for all
// 3 chunk offsets and all ri. Out-of-image tiles (q0>=14 | tyi>=14) read
// zero-filled LDS unconditionally (uniformity), masked at store only.
// ---------------------------------------------------------------------------
__global__ __launch_bounds__(256) void kconv(
    const float* __restrict__ x, const float* __restrict__ wgt,
    const float* __restrict__ bias, float* __restrict__ out)
{
    const int bc  = blockIdx.x;
    const int cch = bc & 255;
    const int tid = threadIdx.x;

    __shared__ __align__(16) float s_p[SROWS * SPITCH + 16];  // 19.2 KB
    __shared__ float s_w[64];

    const float4 z4 = make_float4(0.f, 0.f, 0.f, 0.f);
    for (int i = tid; i < (SROWS * SPITCH + 16) / 4; i += 256) ((float4*)s_p)[i] = z4;
    if (tid < 49) s_w[tid] = wgt[(size_t)bc * 49 + tid];
    __syncthreads();

    // image col ic -> s_p col ic+4; image row iy -> s_p row iy+3.
    const float4* xp4 = (const float4*)(x + (size_t)bc * HWPX);
    for (int i = tid; i < 784; i += 256) {
        const float4 v = xp4[i];
        const int y = i / 14, q = i - y * 14;
        *(float4*)&s_p[(y + 3) * SPITCH + 4 * q + 4] = v;   // aligned b128
    }
    __syncthreads();

    float w[49];
#pragma unroll
    for (int i = 0; i < 49; ++i) w[i] = s_w[i];
    const float bv = bias[cch];

    const int q0  = tid & 15;        // tile col 0..15 (14 valid)
    const int tyi = tid >> 4;        // tile row 0..15 (14 valid)
    const int ty  = tyi * 4;         // s_p base row for reads
    const int tx  = q0 * 4;          // s_p base col (= chunk q0)

    float acc[16];
#pragma unroll
    for (int i = 0; i < 16; ++i) acc[i] = bv;

#pragma unroll
    for (int ri = 0; ri < 10; ++ri) {
        const float* row = &s_p[(ty + ri) * SPITCH + tx];
        const float4 r0 = *(const float4*)(row);        // chunks q0,q0+1,q0+2
        const float4 r1 = *(const float4*)(row + 4);
        const float4 r2 = *(const float4*)(row + 8);
        float rr[12];
        rr[0]=r0.x; rr[1]=r0.y; rr[2]=r0.z;  rr[3]=r0.w;
        rr[4]=r1.x; rr[5]=r1.y; rr[6]=r1.z;  rr[7]=r1.w;
        rr[8]=r2.x; rr[9]=r2.y; rr[10]=r2.z; rr[11]=r2.w;
#pragma unroll
        for (int iy = 0; iy < 4; ++iy) {
            const int ky = ri - iy;
            if (ky < 0 || ky > 6) continue;   // compile-time pruned
#pragma unroll
            for (int ix = 0; ix < 4; ++ix) {
#pragma unroll
                for (int kx = 0; kx < 7; ++kx)
                    acc[iy*4+ix] = fmaf(w[ky*7+kx], rr[ix+kx+1], acc[iy*4+ix]);
            }
        }
    }

    if (q0 < 14 && tyi < 14) {
#pragma unroll
        for (int iy = 0; iy < 4; ++iy) {
            float* op = out + (size_t)bc * HWPX + (ty + iy) * WIDTH + tx;
            *(float4*)op = make_float4(acc[iy*4+0], acc[iy*4+1], acc[iy*4+2], acc[iy*4+3]);
        }
    }
}

// ---------------------------------------------------------------------------
extern "C" void kernel_launch(void* const* d_in, const int* in_sizes, int n_in,
                              void* d_out, int out_size, void* d_ws, size_t ws_size,
                              hipStream_t stream)
{
    const float* x     = (const float*)d_in[0];
    const float* gamma = (const float*)d_in[1];
    const float* beta  = (const float*)d_in[2];
    const float* mean  = (const float*)d_in[3];
    const float* var   = (const float*)d_in[4];
    const float* qw    = (const float*)d_in[5];
    const float* kw    = (const float*)d_in[6];
    const float* bank  = (const float*)d_in[7];
    const float* bias  = (const float*)d_in[8];
    float* out = (float*)d_out;

    // ws layout (34.2 MB): Kpart is dead after ksum, so Pp aliases it.
    float* ws    = (float*)d_ws;
    float* Kpart = ws;                                   // 4*32*3136*16 = 6,422,528 f
    float* Pp    = ws;                                   // alias: 32*28*4096 = 3,670,016 f
    float* Kbuf  = ws + (size_t)NSUB * BATCH * HWPX * NK;   // 1,605,632 f
    float* P     = Kbuf + (size_t)BATCH * HWPX * NK;        //   131,072 f
    float* wgt   = P + (size_t)BATCH * CH * NK;             //   401,408 f

    kkvec<<<dim3(NSUB * 196),   dim3(256), 0, stream>>>(x, gamma, beta, mean, var, kw, Kpart);
    ksum <<<dim3(1568),         dim3(256), 0, stream>>>(Kpart, Kbuf);
    kpmat<<<dim3(BATCH * NSLAB),dim3(256), 0, stream>>>(x, gamma, beta, mean, var, Kbuf, Pp);
    kpred<<<dim3(512),          dim3(256), 0, stream>>>(Pp, P);
    ksoft<<<dim3(BATCH * 8),    dim3(256), 0, stream>>>(P, qw, bank, wgt);
    kconv<<<dim3(BATCH * CH),   dim3(256), 0, stream>>>(x, wgt, bias, out);
}